// Round 18
// baseline (185.993 us; speedup 1.0000x reference)
//
#include <hip/hip_runtime.h>

#define NTH  512
#define XLEN 368
#define NF   112

typedef short bh8 __attribute__((ext_vector_type(8)));
typedef float fv4 __attribute__((ext_vector_type(4)));
typedef float f32x2 __attribute__((ext_vector_type(2)));

// ======== fused-kernel LDS layout (fallback path, u16 offsets) ========
#define IMG_OFF 0
#define IMG_LD  114
#define X0H 12996
#define X1H 14020
#define H1_OFF 15044
#define TOT_E 35228

#define H2_OFF 0
#define H3_OFF 10800
#define H4_F 0
#define FC1_F 600
#define LG_F 652

// ======== split-kernel LDS layouts (u16 offsets) ========
#define KA_TOT 15044          // 30088 B -> 4 blk/CU
#define KB1_TOT 26912         // 53824 B -> 3 blk/CU
#define T_H3 14400
#define KB2_TOT 18496         // 36992 B -> 4 blk/CU

__device__ __forceinline__ unsigned short bfbits(float v) {
  union { __bf16 b; unsigned short u; } c;
  c.b = (__bf16)v;
  return c.u;
}
__device__ __forceinline__ float f_lo(unsigned u) {
  return __uint_as_float(u << 16);
}
__device__ __forceinline__ float f_hi(unsigned u) {
  return __uint_as_float(u & 0xffff0000u);
}

// ---- prep map bodies (device) ----
__device__ __forceinline__ void prepA_item(const float* __restrict__ ww,
                                           int K, int nks, int idx,
                                           bh8* __restrict__ Aarr) {
  int lane = idx & 63;
  int fk = idx >> 6;
  int ks = fk % nks, ft = fk / nks;
  int frow = ft * 16 + (lane & 15);
  int k0 = ks * 32 + 8 * (lane >> 4);
  union { bh8 s; unsigned short h[8]; } o;
  #pragma unroll
  for (int e = 0; e < 8; ++e) {
    int k = k0 + e;
    float v = (k < K) ? ww[(size_t)frow * K + k] : 0.f;
    o.h[e] = bfbits(v);
  }
  Aarr[idx] = o.s;
}

__device__ __forceinline__ void prepW1_item(const float* __restrict__ f1w,
                                            int idx, bh8* __restrict__ w1f) {
  int lane = idx & 63;
  int fk = idx >> 6;
  int ks = fk % 19, ft = fk / 19;
  int oc = ft * 16 + (lane & 15);
  int k0 = ks * 32 + (lane >> 4) * 8;
  union { bh8 s; unsigned short h[8]; } o;
  #pragma unroll
  for (int e = 0; e < 8; ++e) {
    int k = k0 + e;
    o.h[e] = (k < 588) ? bfbits(f1w[(size_t)oc * 588 + k])
                       : (unsigned short)0;
  }
  w1f[idx] = o.s;
}

__device__ __forceinline__ void prepWc_item(const float* __restrict__ c2w,
                                            const float* __restrict__ c3w,
                                            const float* __restrict__ c4w,
                                            int idx, bh8* __restrict__ wcf) {
  int lane = idx & 63;
  int fr = idx >> 6;
  int oc = lane & 15;
  int koff = (lane >> 4) * 8;
  union { bh8 s; unsigned short h[8]; } o;
  if (fr < 3) {
    #pragma unroll
    for (int e = 0; e < 8; ++e) {
      int k = fr * 32 + koff + e;
      int tap = k >> 3, ic = k & 7;
      float v = (oc < 12 && tap < 9 && ic < 6)
                    ? c2w[(oc * 6 + ic) * 9 + tap] : 0.f;
      o.h[e] = bfbits(v);
    }
  } else {
    int m = (fr < 8) ? (fr - 3) : (fr - 8);
    const float* w = (fr < 8) ? c3w : c4w;
    #pragma unroll
    for (int e = 0; e < 8; ++e) {
      int k = m * 32 + koff + e;
      int tap = k >> 4, ic = k & 15;
      float v = (oc < 12 && tap < 9 && ic < 12)
                    ? w[(oc * 12 + ic) * 9 + tap] : 0.f;
      o.h[e] = bfbits(v);
    }
  }
  wcf[idx] = o.s;
}

// ---- fused prep: maps (blocks [0,nblk)) + bounds (7 appended blocks) ----
__global__ void prep_all(const float* __restrict__ ww, int K, int nks,
                         const float* __restrict__ f1w,
                         const float* __restrict__ c2w,
                         const float* __restrict__ c3w,
                         const float* __restrict__ c4w,
                         int nA, int nblk,
                         bh8* __restrict__ Aarr, bh8* __restrict__ w1f,
                         bh8* __restrict__ wcf, int* __restrict__ bnd) {
  __shared__ int slo[256], shi[256];
  const int bid = blockIdx.x, t = threadIdx.x;
  if (bid < nblk) {
    int idx = bid * 256 + t;
    if (idx < nA) prepA_item(ww, K, nks, idx, Aarr);
    else if (idx < nA + 3648) prepW1_item(f1w, idx - nA, w1f);
    else if (idx < nA + 3648 + 832) prepWc_item(c2w, c3w, c4w,
                                                idx - nA - 3648, wcf);
    return;
  }
  int ft = bid - nblk;
  int lo = K, hi = -1;
  for (int m = t; m < 16 * K; m += 256) {
    int f = ft * 16 + m / K, k = m % K;
    if (ww[(size_t)f * K + k] != 0.f) { lo = min(lo, k); hi = max(hi, k); }
  }
  slo[t] = lo; shi[t] = hi;
  __syncthreads();
  for (int s = 128; s > 0; s >>= 1) {
    if (t < s) {
      slo[t] = min(slo[t], slo[t + s]);
      shi[t] = max(shi[t], shi[t + s]);
    }
    __syncthreads();
  }
  if (t == 0) {
    int l = slo[0], h = shi[0];
    if (h < 0) { bnd[2 * ft] = 0; bnd[2 * ft + 1] = 0; }
    else {
      bnd[2 * ft] = l >> 5;
      bnd[2 * ft + 1] = min((h >> 5) + 1, nks);
    }
  }
}

// ---- standalone preps for the fallback path ----
__global__ void prep_A(const float* __restrict__ ww, int K, int nks,
                       bh8* __restrict__ Aarr) {
  int idx = blockIdx.x * 256 + threadIdx.x;
  if (idx < 7 * nks * 64) prepA_item(ww, K, nks, idx, Aarr);
}
__global__ void prep_bounds(const float* __restrict__ ww, int K, int nks,
                            int* __restrict__ bnd) {
  __shared__ int slo[256], shi[256];
  int ft = blockIdx.x, t = threadIdx.x;
  int lo = K, hi = -1;
  for (int m = t; m < 16 * K; m += 256) {
    int f = ft * 16 + m / K, k = m % K;
    if (ww[(size_t)f * K + k] != 0.f) { lo = min(lo, k); hi = max(hi, k); }
  }
  slo[t] = lo; shi[t] = hi;
  __syncthreads();
  for (int s = 128; s > 0; s >>= 1) {
    if (t < s) {
      slo[t] = min(slo[t], slo[t + s]);
      shi[t] = max(shi[t], shi[t + s]);
    }
    __syncthreads();
  }
  if (t == 0) {
    int l = slo[0], h = shi[0];
    if (h < 0) { bnd[2 * ft] = 0; bnd[2 * ft + 1] = 0; }
    else {
      bnd[2 * ft] = l >> 5;
      bnd[2 * ft + 1] = min((h >> 5) + 1, nks);
    }
  }
}

__device__ __forceinline__ void conv4acc(const float (&p)[4][4],
                                         const float (&w9)[9],
                                         float (&acc)[4]) {
  #pragma unroll
  for (int dy = 0; dy < 2; ++dy)
    #pragma unroll
    for (int dx = 0; dx < 2; ++dx) {
      float a = 0.f;
      #pragma unroll
      for (int dr = 0; dr < 3; ++dr)
        #pragma unroll
        for (int dc = 0; dc < 3; ++dc)
          a = fmaf(p[dy + dr][dx + dc], w9[dr * 3 + dc], a);
      acc[dy * 2 + dx] += a;
    }
}

__device__ __forceinline__ void load_patch(const unsigned short* su, int baseEl,
                                           int ldEl, float (&p)[4][4]) {
  #pragma unroll
  for (int i = 0; i < 4; ++i) {
    unsigned a = *(const unsigned*)(su + baseEl + i * ldEl);
    unsigned b = *(const unsigned*)(su + baseEl + i * ldEl + 2);
    p[i][0] = f_lo(a); p[i][1] = f_hi(a);
    p[i][2] = f_lo(b); p[i][3] = f_hi(b);
  }
}

// CWT phase body; hoisted per-tile addressing (parity is ks-invariant).
template <bool PRE>
__device__ __forceinline__ void cwt_phase(unsigned short* su, int tid,
                                          const float* __restrict__ ww,
                                          const bh8* __restrict__ Aarr,
                                          const int* __restrict__ bnd,
                                          int K, int nks) {
  const int wid = __builtin_amdgcn_readfirstlane(tid >> 6);
  const int lane = tid & 63;
  const int koff = (lane >> 4) * 8;
  #pragma unroll 1
  for (int tile = wid; tile < 49; tile += NTH / 64) {
    const int ft = tile / 7, jt = tile - ft * 7;
    int klo = 0, khi = nks;
    if (PRE) { klo = bnd[2 * ft]; khi = bnd[2 * ft + 1]; }
    const int jcol = jt * 16 + (lane & 15);
    const int selj = (jcol == NF - 1)
        ? (XLEN - 1)
        : (int)((double)jcol * ((double)(XLEN - 1) / (double)(NF - 1)));
    fv4 acc = {0.f, 0.f, 0.f, 0.f};
    if (PRE) {
      const int kb0 = selj + (klo << 5) + koff;
      const int par = kb0 & 1;
      const unsigned* ph =
          (const unsigned*)(su + (par ? X1H : X0H) + (kb0 - par));
      const bh8* ap = Aarr + ((size_t)ft * nks + klo) * 64 + lane;
      for (int ks = klo; ks < khi; ++ks) {
        union { bh8 v; unsigned u[4]; } bh_;
        #pragma unroll
        for (int j = 0; j < 4; ++j) bh_.u[j] = ph[j];
        bh8 ah = *ap;
        acc = __builtin_amdgcn_mfma_f32_16x16x32_bf16(ah, bh_.v, acc, 0, 0, 0);
        ph += 16;
        ap += 64;
      }
    } else {
      for (int ks = klo; ks < khi; ++ks) {
        const int kbase = selj + (ks << 5) + koff;
        const int par = kbase & 1;
        const int e0 = kbase - par;
        const unsigned* ph = (const unsigned*)(su + (par ? X1H : X0H) + e0);
        union { bh8 v; unsigned u[4]; } bh_;
        #pragma unroll
        for (int j = 0; j < 4; ++j) bh_.u[j] = ph[j];
        const int frow = ft * 16 + (lane & 15);
        union { bh8 s; unsigned short h[8]; } ha;
        #pragma unroll
        for (int e = 0; e < 8; ++e) {
          int k = (ks << 5) + koff + e;
          float v = (k < K) ? ww[(size_t)frow * K + k] : 0.f;
          ha.h[e] = bfbits(v);
        }
        acc = __builtin_amdgcn_mfma_f32_16x16x32_bf16(ha.s, bh_.v, acc,
                                                      0, 0, 0);
      }
    }
    const int col = jt * 16 + (lane & 15) + 1;
    const int fbase = ft * 16 + (lane >> 4) * 4 + 1;
    #pragma unroll
    for (int r = 0; r < 4; ++r)
      su[IMG_OFF + (fbase + r) * IMG_LD + col] = bfbits(acc[r]);
  }
}

// ================= split kernel A: CWT + conv1 -> h1 (global) ==========
// h1g layout: PLANE-major u32: h1u[plane][3136], plane=0..2 (bf16 pairs).
__global__ __launch_bounds__(NTH, 4) void k_cwt_conv1(
    const float* __restrict__ x, const bh8* __restrict__ Aarr,
    const int* __restrict__ bnd, int K, int nks,
    const float* __restrict__ c1w, const float* __restrict__ c1b,
    unsigned* __restrict__ h1g) {
  extern __shared__ unsigned short su[];
  const int b = blockIdx.x;
  const int tid = threadIdx.x;
  const int pad = (K - 1) >> 1;

  for (int m = tid; m < 452; m += NTH) {  // img halo ring
    int r, c;
    if (m < 114) { r = 0; c = m; }
    else if (m < 228) { r = 113; c = m - 114; }
    else if (m < 340) { r = m - 228 + 1; c = 0; }
    else { r = m - 340 + 1; c = 113; }
    su[IMG_OFF + r * IMG_LD + c] = 0;
  }
  for (int i = tid; i < 1024; i += NTH) {
    float f0 = 0.f, f1 = 0.f;
    int xi = i - pad;
    if (xi >= 0 && xi < XLEN) f0 = x[(size_t)b * XLEN + xi];
    if (xi + 1 >= 0 && xi + 1 < XLEN) f1 = x[(size_t)b * XLEN + xi + 1];
    su[X0H + i] = bfbits(f0);
    su[X1H + i] = bfbits(f1);
  }
  __syncthreads();

  cwt_phase<true>(su, tid, nullptr, Aarr, bnd, K, nks);
  __syncthreads();

  // conv1 packed-f32, strip-of-2 pooled points -> h1 plane-major
  unsigned* h1s = h1g + (size_t)b * 9408;
  for (int s = tid; s < 1568; s += NTH) {
    int sr = s / 28, sc = s - sr * 28;   // pooled row, strip col
    int r0 = sr * 2, c0 = sc * 4;        // patch origin
    // load 4 rows x 6 cols
    float pv[4][6];
    #pragma unroll
    for (int i = 0; i < 4; ++i) {
      const unsigned* rp = (const unsigned*)(su + (r0 + i) * IMG_LD + c0);
      unsigned a = rp[0], bq = rp[1], cq = rp[2];
      pv[i][0] = f_lo(a);  pv[i][1] = f_hi(a);
      pv[i][2] = f_lo(bq); pv[i][3] = f_hi(bq);
      pv[i][4] = f_lo(cq); pv[i][5] = f_hi(cq);
    }
    union { uint2 w2[3]; unsigned short h[12]; } ou;  // h[2p+..]: A/B pairs
    #pragma unroll
    for (int oc = 0; oc < 6; ++oc) {
      f32x2 a0 = {c1b[oc], c1b[oc]}, a1 = a0;  // point A (cols c0..)
      f32x2 b0 = a0, b1 = a0;                  // point B (cols c0+2..)
      #pragma unroll
      for (int dr = 0; dr < 3; ++dr)
        #pragma unroll
        for (int dc = 0; dc < 3; ++dc) {
          float w = c1w[oc * 9 + dr * 3 + dc];
          f32x2 wv = {w, w};
          f32x2 pA0 = {pv[dr][dc], pv[dr][dc + 1]};
          f32x2 pA1 = {pv[dr + 1][dc], pv[dr + 1][dc + 1]};
          f32x2 pB0 = {pv[dr][dc + 2], pv[dr][dc + 3]};
          f32x2 pB1 = {pv[dr + 1][dc + 2], pv[dr + 1][dc + 3]};
          a0 = __builtin_elementwise_fma(pA0, wv, a0);
          a1 = __builtin_elementwise_fma(pA1, wv, a1);
          b0 = __builtin_elementwise_fma(pB0, wv, b0);
          b1 = __builtin_elementwise_fma(pB1, wv, b1);
        }
      float mA = fmaxf(fmaxf(a0.x, a0.y), fmaxf(a1.x, a1.y));
      float mB = fmaxf(fmaxf(b0.x, b0.y), fmaxf(b1.x, b1.y));
      // word layout: plane w holds ocs (2w,2w+1); A then B consecutive pts
      int w = oc >> 1, hi = oc & 1;
      ou.h[w * 4 + hi] = bfbits(fmaxf(mA, 0.f));
      ou.h[w * 4 + 2 + hi] = bfbits(fmaxf(mB, 0.f));
    }
    int ptA = sr * 56 + sc * 2;
    #pragma unroll
    for (int w = 0; w < 3; ++w)
      *(uint2*)(h1s + w * 3136 + ptA) = ou.w2[w];
  }
}

// ================= split kernel B1: conv2 -> h2 (global) ===============
__global__ __launch_bounds__(NTH, 4) void k_conv2(
    const unsigned* __restrict__ h1g, const bh8* __restrict__ wcf,
    const float* __restrict__ c2b, unsigned* __restrict__ h2g) {
  extern __shared__ unsigned short su[];
  unsigned* su32 = (unsigned*)su;
  const int b = blockIdx.x;
  const int tid = threadIdx.x;
  const int lane = tid & 63, wid = tid >> 6;
  const int oc_a = lane & 15;
  const int row0 = (lane >> 4) * 4;

  for (int m = tid; m < 228; m += NTH) {  // halo ring
    int r, c;
    if (m < 58) { r = 0; c = m; }
    else if (m < 116) { r = 57; c = m - 58; }
    else if (m < 172) { r = m - 116 + 1; c = 0; }
    else { r = m - 172 + 1; c = 57; }
    ((uint4*)su)[r * 58 + c] = uint4{0, 0, 0, 0};
  }
  {
    const unsigned* g = h1g + (size_t)b * 9408;
    for (int i2 = tid; i2 < 9408; i2 += NTH) {
      int plane = i2 / 3136, pt = i2 - plane * 3136;
      int pr = pt / 56, pc = pt - pr * 56;
      su32[((pr + 1) * 58 + (pc + 1)) * 4 + plane] = g[i2];
    }
    for (int pt = tid; pt < 3136; pt += NTH) {
      int pr = pt / 56, pc = pt - pr * 56;
      su32[((pr + 1) * 58 + (pc + 1)) * 4 + 3] = 0;
    }
  }
  bh8 afr[3];
  #pragma unroll
  for (int m = 0; m < 3; ++m) afr[m] = wcf[m * 64 + lane];
  float biasv[4];
  #pragma unroll
  for (int r = 0; r < 4; ++r)
    biasv[r] = (row0 + r < 12) ? c2b[row0 + r] : 0.f;
  __syncthreads();

  unsigned* h2s = h2g + (size_t)b * 4704;
  for (int t = wid; t < 196; t += NTH / 64) {
    int n = t * 16 + oc_a;
    int p = n >> 2, q = n & 3;
    int pr = p / 28, pc = p - pr * 28;
    int r = pr * 2 + (q >> 1), c = pc * 2 + (q & 1);
    int base = (r * 58 + c) * 8;
    fv4 acc = {biasv[0], biasv[1], biasv[2], biasv[3]};
    #pragma unroll
    for (int m = 0; m < 3; ++m) {
      int tap = m * 4 + (lane >> 4);
      if (tap > 8) tap = 8;
      int dr = tap / 3, dc = tap - dr * 3;
      bh8 bv = *(const bh8*)(su + base + (dr * 58 + dc) * 8);
      acc = __builtin_amdgcn_mfma_f32_16x16x32_bf16(afr[m], bv, acc, 0, 0, 0);
    }
    union { uint2 v; unsigned short h[4]; } ou;
    #pragma unroll
    for (int r4 = 0; r4 < 4; ++r4) {
      float v = acc[r4];
      v = fmaxf(v, __shfl_xor(v, 1));
      v = fmaxf(v, __shfl_xor(v, 2));
      ou.h[r4] = bfbits(fmaxf(v, 0.f));
    }
    if ((lane & 3) == 0 && row0 < 12) {
      int w = row0 >> 1;  // 0,2,4
      h2s[w * 784 + p] = ou.v.x;
      h2s[(w + 1) * 784 + p] = ou.v.y;
    }
  }
}

// ============ split kernel B2: conv3+conv4 -> h4 (global bf16) =========
__global__ __launch_bounds__(NTH, 4) void k_tail(
    const unsigned* __restrict__ h2g, const bh8* __restrict__ wcf,
    const float* __restrict__ c3b, const float* __restrict__ c4b,
    unsigned short* __restrict__ h4g) {
  extern __shared__ unsigned short su[];
  unsigned* su32 = (unsigned*)su;
  const int b = blockIdx.x;
  const int tid = threadIdx.x;
  const int lane = tid & 63, wid = tid >> 6;
  const int oc_a = lane & 15;
  const int koff = (lane >> 4) * 8;
  const int row0 = (lane >> 4) * 4;
  const int icoff = koff & 15;
  const int taphalf = koff >> 4;

  for (int m = tid; m < 116; m += NTH) {
    int r, c;
    if (m < 30) { r = 0; c = m; }
    else if (m < 60) { r = 29; c = m - 30; }
    else if (m < 88) { r = m - 60 + 1; c = 0; }
    else { r = m - 88 + 1; c = 29; }
    ((uint4*)su)[(r * 30 + c) * 2] = uint4{0, 0, 0, 0};
    ((uint4*)su)[(r * 30 + c) * 2 + 1] = uint4{0, 0, 0, 0};
  }
  for (int m = tid; m < 60; m += NTH) {
    int r, c;
    if (m < 16) { r = 0; c = m; }
    else if (m < 32) { r = 15; c = m - 16; }
    else if (m < 46) { r = m - 32 + 1; c = 0; }
    else { r = m - 46 + 1; c = 15; }
    ((uint4*)(su + T_H3))[(r * 16 + c) * 2] = uint4{0, 0, 0, 0};
    ((uint4*)(su + T_H3))[(r * 16 + c) * 2 + 1] = uint4{0, 0, 0, 0};
  }
  {
    const unsigned* g = h2g + (size_t)b * 4704;
    for (int i2 = tid; i2 < 4704; i2 += NTH) {
      int plane = i2 / 784, pt = i2 - plane * 784;
      int pr = pt / 28, pc = pt - pr * 28;
      su32[((pr + 1) * 30 + (pc + 1)) * 8 + plane] = g[i2];
    }
    for (int m = tid; m < 1568; m += NTH) {
      int pt = m >> 1, w = 6 + (m & 1);
      int pr = pt / 28, pc = pt - pr * 28;
      su32[((pr + 1) * 30 + (pc + 1)) * 8 + w] = 0;
    }
  }
  bh8 a3[5], a4[5];
  #pragma unroll
  for (int m = 0; m < 5; ++m) a3[m] = wcf[(3 + m) * 64 + lane];
  #pragma unroll
  for (int m = 0; m < 5; ++m) a4[m] = wcf[(8 + m) * 64 + lane];
  float bias3[4], bias4[4];
  #pragma unroll
  for (int r = 0; r < 4; ++r) {
    bias3[r] = (row0 + r < 12) ? c3b[row0 + r] : 0.f;
    bias4[r] = (row0 + r < 12) ? c4b[row0 + r] : 0.f;
  }
  __syncthreads();

  for (int t = wid; t < 49; t += NTH / 64) {
    int n = t * 16 + oc_a;
    int p = n >> 2, q = n & 3;
    int pr = p / 14, pc = p - pr * 14;
    int r = pr * 2 + (q >> 1), c = pc * 2 + (q & 1);
    int base = (r * 30 + c) * 16 + icoff;
    fv4 acc = {bias3[0], bias3[1], bias3[2], bias3[3]};
    #pragma unroll
    for (int m = 0; m < 5; ++m) {
      int tap = m * 2 + taphalf;
      if (tap > 8) tap = 8;
      int dr = tap / 3, dc = tap - dr * 3;
      bh8 bv = *(const bh8*)(su + base + (dr * 30 + dc) * 16);
      acc = __builtin_amdgcn_mfma_f32_16x16x32_bf16(a3[m], bv, acc, 0, 0, 0);
    }
    union { uint2 v; unsigned short h[4]; } ou;
    #pragma unroll
    for (int r4 = 0; r4 < 4; ++r4) {
      float v = acc[r4];
      v = fmaxf(v, __shfl_xor(v, 1));
      v = fmaxf(v, __shfl_xor(v, 2));
      ou.h[r4] = bfbits(fmaxf(v, 0.f));
    }
    if ((lane & 3) == 0)
      *(uint2*)(su + T_H3 + ((pr + 1) * 16 + (pc + 1)) * 16 + row0) = ou.v;
  }
  __syncthreads();

  unsigned short* h4s = h4g + (size_t)b * 608;
  for (int t = wid; t < 13; t += NTH / 64) {
    int n = t * 16 + oc_a;
    int p = n >> 2, q = n & 3;
    int pp = (p < 49) ? p : 0;
    int pr = pp / 7, pc = pp - pr * 7;
    int r = pr * 2 + (q >> 1), c = pc * 2 + (q & 1);
    int base = T_H3 + (r * 16 + c) * 16 + icoff;
    fv4 acc = {bias4[0], bias4[1], bias4[2], bias4[3]};
    #pragma unroll
    for (int m = 0; m < 5; ++m) {
      int tap = m * 2 + taphalf;
      if (tap > 8) tap = 8;
      int dr = tap / 3, dc = tap - dr * 3;
      bh8 bv = *(const bh8*)(su + base + (dr * 16 + dc) * 16);
      acc = __builtin_amdgcn_mfma_f32_16x16x32_bf16(a4[m], bv, acc, 0, 0, 0);
    }
    #pragma unroll
    for (int r4 = 0; r4 < 4; ++r4) {
      float v = acc[r4];
      v = fmaxf(v, __shfl_xor(v, 1));
      v = fmaxf(v, __shfl_xor(v, 2));
      v = fmaxf(v, 0.f);
      int oc = row0 + r4;
      if ((lane & 3) == 0 && p < 49 && oc < 12)
        h4s[oc * 49 + pr * 7 + pc] = bfbits(v);
    }
  }
}

// ============ k_fc: batched fc1 (MFMA) + fc2 + softmax ============
__global__ __launch_bounds__(64) void k_fc(
    const unsigned short* __restrict__ h4g, const bh8* __restrict__ w1f,
    const float* __restrict__ f1b, const float* __restrict__ f2w,
    const float* __restrict__ f2b, int nsamp, float* __restrict__ out) {
  __shared__ float fcs[16][49];
  const int lane = threadIdx.x;
  const int sbase = blockIdx.x * 16;
  const int scol = lane & 15;
  const int koff = (lane >> 4) * 8;
  const int row0 = (lane >> 4) * 4;
  int srow = sbase + scol;
  if (srow >= nsamp) srow = nsamp - 1;
  const unsigned short* hrow = h4g + (size_t)srow * 608 + koff;

  fv4 acc[3];
  #pragma unroll
  for (int ft = 0; ft < 3; ++ft) acc[ft] = fv4{0.f, 0.f, 0.f, 0.f};
  for (int ks = 0; ks < 19; ++ks) {
    bh8 bv = *(const bh8*)(hrow + ks * 32);
    #pragma unroll
    for (int ft = 0; ft < 3; ++ft) {
      bh8 av = w1f[(ft * 19 + ks) * 64 + lane];
      acc[ft] = __builtin_amdgcn_mfma_f32_16x16x32_bf16(av, bv, acc[ft],
                                                        0, 0, 0);
    }
  }
  #pragma unroll
  for (int ft = 0; ft < 3; ++ft)
    #pragma unroll
    for (int r = 0; r < 4; ++r) {
      int oc = ft * 16 + row0 + r;
      fcs[scol][oc] = fmaxf(acc[ft][r] + f1b[oc], 0.f);
    }
  __syncthreads();
  if (lane < 16 && sbase + lane < nsamp) {
    float l[4];
    #pragma unroll
    for (int o = 0; o < 4; ++o) {
      float s = f2b[o];
      for (int i = 0; i < 48; ++i) s += fcs[lane][i] * f2w[o * 48 + i];
      l[o] = s;
    }
    float m = fmaxf(fmaxf(l[0], l[1]), fmaxf(l[2], l[3]));
    float e0 = expf(l[0] - m), e1 = expf(l[1] - m);
    float e2 = expf(l[2] - m), e3 = expf(l[3] - m);
    float ss = e0 + e1 + e2 + e3;
    float* o4 = out + (size_t)(sbase + lane) * 4;
    o4[0] = e0 / ss; o4[1] = e1 / ss; o4[2] = e2 / ss; o4[3] = e3 / ss;
  }
}

// ================= fused fallback (register-table conv) ================
template <int NKS, int KREAL, int NOC, int OMODE>
__device__ __forceinline__ void conv_mfma(
    unsigned short* su, float* sfl, unsigned short* gout, int tid,
    int inOff, int inLD, int inCh,
    int outOff, int outLD, int outCh, int plW,
    int NT, int NPOOL,
    const float* __restrict__ wgt, const float* __restrict__ bias) {
  const int lane = tid & 63;
  const int wid = tid >> 6;
  const int oc_a = lane & 15;
  const int koff = (lane >> 4) * 8;
  const int row0 = (lane >> 4) * 4;

  bh8 afr[NKS];
  unsigned opk[NKS][4];
  #pragma unroll
  for (int ks = 0; ks < NKS; ++ks) {
    union { bh8 s; unsigned short h[8]; } au;
    #pragma unroll
    for (int e = 0; e < 8; ++e) {
      int k = ks * 32 + koff + e;
      au.h[e] = (oc_a < NOC && k < KREAL)
                    ? bfbits(wgt[oc_a * KREAL + k]) : (unsigned short)0;
    }
    afr[ks] = au.s;
    #pragma unroll
    for (int e2 = 0; e2 < 4; ++e2) {
      unsigned o01[2];
      #pragma unroll
      for (int h = 0; h < 2; ++h) {
        int k = ks * 32 + koff + 2 * e2 + h;
        int kc = (k < KREAL) ? k : 0;
        int ic = kc / 9, rem = kc - ic * 9;
        o01[h] = (unsigned)(ic * inCh + (rem / 3) * inLD +
                            (rem - (rem / 3) * 3));
      }
      opk[ks][e2] = o01[0] | (o01[1] << 16);
    }
  }
  float biasv[4];
  #pragma unroll
  for (int r = 0; r < 4; ++r)
    biasv[r] = (row0 + r < NOC) ? bias[row0 + r] : 0.f;

  for (int t = wid; t < NT; t += NTH / 64) {
    int n = t * 16 + oc_a;
    int p = n >> 2, q = n & 3;
    int pp = (p < NPOOL) ? p : 0;
    int pr = pp / plW, pc = pp - pr * plW;
    int r = pr * 2 + (q >> 1), c = pc * 2 + (q & 1);
    int base = inOff + r * inLD + c;
    fv4 acc = {biasv[0], biasv[1], biasv[2], biasv[3]};
    #pragma unroll
    for (int ks = 0; ks < NKS; ++ks) {
      union { bh8 v; unsigned short h[8]; } bu;
      #pragma unroll
      for (int e2 = 0; e2 < 4; ++e2) {
        unsigned pk = opk[ks][e2];
        bu.h[2 * e2] = su[base + (pk & 0xffffu)];
        bu.h[2 * e2 + 1] = su[base + (pk >> 16)];
      }
      acc = __builtin_amdgcn_mfma_f32_16x16x32_bf16(afr[ks], bu.v, acc, 0, 0, 0);
    }
    #pragma unroll
    for (int r4 = 0; r4 < 4; ++r4) {
      float v = acc[r4];
      v = fmaxf(v, __shfl_xor(v, 1));
      v = fmaxf(v, __shfl_xor(v, 2));
      v = fmaxf(v, 0.f);
      int oc = row0 + r4;
      if ((lane & 3) == 0 && oc < NOC && p < NPOOL) {
        if (OMODE == 1)
          sfl[outOff + oc * (plW * plW) + pr * plW + pc] = v;
        else if (OMODE == 2)
          gout[oc * NPOOL + pr * plW + pc] = bfbits(v);
        else
          su[outOff + oc * outCh + (pr + 1) * outLD + (pc + 1)] = bfbits(v);
      }
    }
  }
}

template <bool PRE>
__global__ __launch_bounds__(NTH, 4) void fused_convnet(
    const float* __restrict__ x, const float* __restrict__ ww,
    const bh8* __restrict__ Aarr, const int* __restrict__ bnd,
    int K, int nks,
    const float* __restrict__ c1w, const float* __restrict__ c1b,
    const float* __restrict__ c2w, const float* __restrict__ c2b,
    const float* __restrict__ c3w, const float* __restrict__ c3b,
    const float* __restrict__ c4w, const float* __restrict__ c4b,
    const float* __restrict__ f1w, const float* __restrict__ f1b,
    const float* __restrict__ f2w, const float* __restrict__ f2b,
    float* __restrict__ out) {
  extern __shared__ unsigned short su[];
  float* sfl = (float*)su;
  const int b = blockIdx.x;
  const int tid = threadIdx.x;
  const int pad = (K - 1) >> 1;

  for (int m = tid; m < 452; m += NTH) {
    int r, c;
    if (m < 114) { r = 0; c = m; }
    else if (m < 228) { r = 113; c = m - 114; }
    else if (m < 340) { r = m - 228 + 1; c = 0; }
    else { r = m - 340 + 1; c = 113; }
    su[IMG_OFF + r * IMG_LD + c] = 0;
  }
  for (int m = tid; m < 1368; m += NTH) {
    int ch = m / 228, w = m - ch * 228, r, c;
    if (w < 58) { r = 0; c = w; }
    else if (w < 116) { r = 57; c = w - 58; }
    else if (w < 172) { r = w - 116 + 1; c = 0; }
    else { r = w - 172 + 1; c = 57; }
    su[H1_OFF + ch * 3364 + r * 58 + c] = 0;
  }
  for (int i = tid; i < 1024; i += NTH) {
    float f0 = 0.f, f1 = 0.f;
    int xi = i - pad;
    if (xi >= 0 && xi < XLEN) f0 = x[(size_t)b * XLEN + xi];
    if (xi + 1 >= 0 && xi + 1 < XLEN) f1 = x[(size_t)b * XLEN + xi + 1];
    su[X0H + i] = bfbits(f0);
    su[X1H + i] = bfbits(f1);
  }
  __syncthreads();

  cwt_phase<PRE>(su, tid, ww, Aarr, bnd, K, nks);
  __syncthreads();

  for (int it = tid; it < 3136; it += NTH) {
    int pr = it / 56, pc = it - pr * 56;
    float p[4][4];
    load_patch(su, IMG_OFF + (pr * 2) * IMG_LD + pc * 2, IMG_LD, p);
    #pragma unroll
    for (int oc = 0; oc < 6; ++oc) {
      float w9[9];
      #pragma unroll
      for (int t = 0; t < 9; ++t) w9[t] = c1w[oc * 9 + t];
      float acc[4] = {c1b[oc], c1b[oc], c1b[oc], c1b[oc]};
      conv4acc(p, w9, acc);
      float m = fmaxf(fmaxf(acc[0], acc[1]), fmaxf(acc[2], acc[3]));
      su[H1_OFF + oc * 3364 + (pr + 1) * 58 + (pc + 1)] = bfbits(fmaxf(m, 0.f));
    }
  }
  __syncthreads();

  for (int m = tid; m < 1392; m += NTH) {
    int ch = m / 116, w = m - ch * 116, r, c;
    if (w < 30) { r = 0; c = w; }
    else if (w < 60) { r = 29; c = w - 30; }
    else if (w < 88) { r = w - 60 + 1; c = 0; }
    else { r = w - 88 + 1; c = 29; }
    su[H2_OFF + ch * 900 + r * 30 + c] = 0;
  }
  for (int m = tid; m < 720; m += NTH) {
    int ch = m / 60, w = m - ch * 60, r, c;
    if (w < 16) { r = 0; c = w; }
    else if (w < 32) { r = 15; c = w - 16; }
    else if (w < 46) { r = w - 32 + 1; c = 0; }
    else { r = w - 46 + 1; c = 15; }
    su[H3_OFF + ch * 256 + r * 16 + c] = 0;
  }
  __syncthreads();

  conv_mfma<2, 54, 12, 0>(su, sfl, nullptr, tid, H1_OFF, 58, 3364,
                          H2_OFF, 30, 900, 28, 196, 784, c2w, c2b);
  __syncthreads();

  conv_mfma<4, 108, 12, 0>(su, sfl, nullptr, tid, H2_OFF, 30, 900,
                           H3_OFF, 16, 256, 14, 49, 196, c3w, c3b);
  __syncthreads();

  conv_mfma<4, 108, 12, 1>(su, sfl, nullptr, tid, H3_OFF, 16, 256,
                           H4_F, 0, 0, 7, 13, 49, c4w, c4b);
  __syncthreads();

  {
    int wv = tid >> 6, ln = tid & 63;
    for (int o = wv; o < 48; o += NTH / 64) {
      float s = 0.f;
      for (int i = ln; i < 588; i += 64)
        s += sfl[H4_F + i] * f1w[(size_t)o * 588 + i];
      #pragma unroll
      for (int off = 32; off > 0; off >>= 1) s += __shfl_down(s, off);
      if (ln == 0) sfl[FC1_F + o] = fmaxf(s + f1b[o], 0.f);
    }
  }
  __syncthreads();
  if (tid < 4) {
    float s = f2b[tid];
    for (int i = 0; i < 48; ++i) s += sfl[FC1_F + i] * f2w[tid * 48 + i];
    sfl[LG_F + tid] = s;
  }
  __syncthreads();
  if (tid < 4) {
    float l0 = sfl[LG_F + 0], l1 = sfl[LG_F + 1];
    float l2 = sfl[LG_F + 2], l3 = sfl[LG_F + 3];
    float m = fmaxf(fmaxf(l0, l1), fmaxf(l2, l3));
    float e0 = expf(l0 - m), e1 = expf(l1 - m);
    float e2 = expf(l2 - m), e3 = expf(l3 - m);
    float ssum = e0 + e1 + e2 + e3;
    out[(size_t)b * 4 + tid] = expf(sfl[LG_F + tid] - m) / ssum;
  }
}

extern "C" void kernel_launch(void* const* d_in, const int* in_sizes, int n_in,
                              void* d_out, int out_size, void* d_ws,
                              size_t ws_size, hipStream_t stream) {
  const float* x   = (const float*)d_in[0];
  const float* ww  = (const float*)d_in[1];
  const float* c1w = (const float*)d_in[2];
  const float* c1b = (const float*)d_in[3];
  const float* c2w = (const float*)d_in[4];
  const float* c2b = (const float*)d_in[5];
  const float* c3w = (const float*)d_in[6];
  const float* c3b = (const float*)d_in[7];
  const float* c4w = (const float*)d_in[8];
  const float* c4b = (const float*)d_in[9];
  const float* f1w = (const float*)d_in[10];
  const float* f1b = (const float*)d_in[11];
  const float* f2w = (const float*)d_in[12];
  const float* f2b = (const float*)d_in[13];
  float* out = (float*)d_out;

  const int B = in_sizes[0] / XLEN;
  const int K = in_sizes[1] / NF;  // 561
  const int nks = (K + 31) / 32;   // 18

  const int items = 7 * nks * 64;
  const size_t aoff = (size_t)items * sizeof(bh8);   // 129024 B
  const size_t abytes = aoff + 64;                   // + bnd
  const size_t w1off = abytes;
  const size_t w1bytes = (size_t)3648 * sizeof(bh8); // 58368 B
  const size_t wcoff = w1off + w1bytes;
  const size_t wcbytes = (size_t)832 * sizeof(bh8);  // 13312 B
  const size_t h1off = wcoff + wcbytes;
  const size_t h1bytes = (size_t)B * 18816 * 2;
  const size_t h2off = h1off + h1bytes;
  const size_t h2bytes = (size_t)B * 9408 * 2;
  const size_t h4off = h2off + h2bytes;
  const size_t h4bytes = (size_t)B * 608 * 2;
  const size_t need3 = h4off + h4bytes;

  bh8* Aarr = (bh8*)d_ws;
  int* bnd = (int*)((char*)d_ws + aoff);
  bh8* w1f = (bh8*)((char*)d_ws + w1off);
  bh8* wcf = (bh8*)((char*)d_ws + wcoff);
  unsigned* h1g = (unsigned*)((char*)d_ws + h1off);
  unsigned* h2g = (unsigned*)((char*)d_ws + h2off);
  unsigned short* h4g = (unsigned short*)((char*)d_ws + h4off);

  if (ws_size >= need3) {
    const int nmap = items + 3648 + 832;
    const int nblk = (nmap + 255) / 256;
    hipLaunchKernelGGL(prep_all, dim3(nblk + 7), dim3(256), 0, stream,
                       ww, K, nks, f1w, c2w, c3w, c4w, items, nblk,
                       Aarr, w1f, wcf, bnd);
    hipFuncSetAttribute((const void*)k_cwt_conv1,
                        hipFuncAttributeMaxDynamicSharedMemorySize,
                        KA_TOT * 2);
    hipFuncSetAttribute((const void*)k_conv2,
                        hipFuncAttributeMaxDynamicSharedMemorySize,
                        KB1_TOT * 2);
    hipFuncSetAttribute((const void*)k_tail,
                        hipFuncAttributeMaxDynamicSharedMemorySize,
                        KB2_TOT * 2);
    hipLaunchKernelGGL(k_cwt_conv1, dim3(B), dim3(NTH), KA_TOT * 2, stream,
                       x, Aarr, bnd, K, nks, c1w, c1b, h1g);
    hipLaunchKernelGGL(k_conv2, dim3(B), dim3(NTH), KB1_TOT * 2, stream,
                       h1g, wcf, c2b, h2g);
    hipLaunchKernelGGL(k_tail, dim3(B), dim3(NTH), KB2_TOT * 2, stream,
                       h2g, wcf, c3b, c4b, h4g);
    hipLaunchKernelGGL(k_fc, dim3((B + 15) / 16), dim3(64), 0, stream,
                       h4g, w1f, f1b, f2w, f2b, B, out);
  } else if (ws_size >= abytes) {
    hipLaunchKernelGGL(prep_A, dim3((items + 255) / 256), dim3(256), 0, stream,
                       ww, K, nks, Aarr);
    hipLaunchKernelGGL(prep_bounds, dim3(7), dim3(256), 0, stream,
                       ww, K, nks, bnd);
    hipFuncSetAttribute((const void*)fused_convnet<true>,
                        hipFuncAttributeMaxDynamicSharedMemorySize,
                        TOT_E * 2);
    hipLaunchKernelGGL(fused_convnet<true>, dim3(B), dim3(NTH), TOT_E * 2,
                       stream, x, ww, Aarr, bnd, K, nks, c1w, c1b, c2w, c2b,
                       c3w, c3b, c4w, c4b, f1w, f1b, f2w, f2b, out);
  } else {
    hipFuncSetAttribute((const void*)fused_convnet<false>,
                        hipFuncAttributeMaxDynamicSharedMemorySize,
                        TOT_E * 2);
    hipLaunchKernelGGL(fused_convnet<false>, dim3(B), dim3(NTH), TOT_E * 2,
                       stream, x, ww, Aarr, bnd, K, nks, c1w, c1b, c2w, c2b,
                       c3w, c3b, c4w, c4b, f1w, f1b, f2w, f2b, out);
  }
}

// Round 19
// 181.870 us; speedup vs baseline: 1.0227x; 1.0227x over previous
//
#include <hip/hip_runtime.h>

#define NTH  512
#define XLEN 368
#define NF   112

typedef short bh8 __attribute__((ext_vector_type(8)));
typedef float fv4 __attribute__((ext_vector_type(4)));
typedef float f32x2 __attribute__((ext_vector_type(2)));

// ======== fused-kernel LDS layout (fallback path, u16 offsets) ========
#define IMG_OFF 0
#define IMG_LD  114
#define X0H 12996
#define X1H 14020
#define H1_OFF 15044
#define TOT_E 35228

#define H2_OFF 0
#define H3_OFF 10800
#define H4_F 0
#define FC1_F 600
#define LG_F 652

// ======== split-kernel LDS layouts (u16 offsets) ========
#define KA_TOT 15044          // 30088 B -> 4 blk/CU
#define KB1_TOT 26912         // 53824 B -> 3 blk/CU
#define T_H3 14400
#define KB2_TOT 18496         // 36992 B -> 4 blk/CU

__device__ __forceinline__ unsigned short bfbits(float v) {
  union { __bf16 b; unsigned short u; } c;
  c.b = (__bf16)v;
  return c.u;
}
__device__ __forceinline__ float f_lo(unsigned u) {
  return __uint_as_float(u << 16);
}
__device__ __forceinline__ float f_hi(unsigned u) {
  return __uint_as_float(u & 0xffff0000u);
}

// ---- prep map bodies (device) ----
__device__ __forceinline__ void prepA_item(const float* __restrict__ ww,
                                           int K, int nks, int idx,
                                           bh8* __restrict__ Aarr) {
  int lane = idx & 63;
  int fk = idx >> 6;
  int ks = fk % nks, ft = fk / nks;
  int frow = ft * 16 + (lane & 15);
  int k0 = ks * 32 + 8 * (lane >> 4);
  union { bh8 s; unsigned short h[8]; } o;
  #pragma unroll
  for (int e = 0; e < 8; ++e) {
    int k = k0 + e;
    float v = (k < K) ? ww[(size_t)frow * K + k] : 0.f;
    o.h[e] = bfbits(v);
  }
  Aarr[idx] = o.s;
}

__device__ __forceinline__ void prepW1_item(const float* __restrict__ f1w,
                                            int idx, bh8* __restrict__ w1f) {
  int lane = idx & 63;
  int fk = idx >> 6;
  int ks = fk % 19, ft = fk / 19;
  int oc = ft * 16 + (lane & 15);
  int k0 = ks * 32 + (lane >> 4) * 8;
  union { bh8 s; unsigned short h[8]; } o;
  #pragma unroll
  for (int e = 0; e < 8; ++e) {
    int k = k0 + e;
    o.h[e] = (k < 588) ? bfbits(f1w[(size_t)oc * 588 + k])
                       : (unsigned short)0;
  }
  w1f[idx] = o.s;
}

__device__ __forceinline__ void prepWc_item(const float* __restrict__ c2w,
                                            const float* __restrict__ c3w,
                                            const float* __restrict__ c4w,
                                            int idx, bh8* __restrict__ wcf) {
  int lane = idx & 63;
  int fr = idx >> 6;
  int oc = lane & 15;
  int koff = (lane >> 4) * 8;
  union { bh8 s; unsigned short h[8]; } o;
  if (fr < 3) {
    #pragma unroll
    for (int e = 0; e < 8; ++e) {
      int k = fr * 32 + koff + e;
      int tap = k >> 3, ic = k & 7;
      float v = (oc < 12 && tap < 9 && ic < 6)
                    ? c2w[(oc * 6 + ic) * 9 + tap] : 0.f;
      o.h[e] = bfbits(v);
    }
  } else {
    int m = (fr < 8) ? (fr - 3) : (fr - 8);
    const float* w = (fr < 8) ? c3w : c4w;
    #pragma unroll
    for (int e = 0; e < 8; ++e) {
      int k = m * 32 + koff + e;
      int tap = k >> 4, ic = k & 15;
      float v = (oc < 12 && tap < 9 && ic < 12)
                    ? w[(oc * 12 + ic) * 9 + tap] : 0.f;
      o.h[e] = bfbits(v);
    }
  }
  wcf[idx] = o.s;
}

// ---- fused prep: maps (blocks [0,nblk)) + bounds (7 appended blocks) ----
__global__ void prep_all(const float* __restrict__ ww, int K, int nks,
                         const float* __restrict__ f1w,
                         const float* __restrict__ c2w,
                         const float* __restrict__ c3w,
                         const float* __restrict__ c4w,
                         int nA, int nblk,
                         bh8* __restrict__ Aarr, bh8* __restrict__ w1f,
                         bh8* __restrict__ wcf, int* __restrict__ bnd) {
  __shared__ int slo[256], shi[256];
  const int bid = blockIdx.x, t = threadIdx.x;
  if (bid < nblk) {
    int idx = bid * 256 + t;
    if (idx < nA) prepA_item(ww, K, nks, idx, Aarr);
    else if (idx < nA + 3648) prepW1_item(f1w, idx - nA, w1f);
    else if (idx < nA + 3648 + 832) prepWc_item(c2w, c3w, c4w,
                                                idx - nA - 3648, wcf);
    return;
  }
  int ft = bid - nblk;
  int lo = K, hi = -1;
  for (int m = t; m < 16 * K; m += 256) {
    int f = ft * 16 + m / K, k = m % K;
    if (ww[(size_t)f * K + k] != 0.f) { lo = min(lo, k); hi = max(hi, k); }
  }
  slo[t] = lo; shi[t] = hi;
  __syncthreads();
  for (int s = 128; s > 0; s >>= 1) {
    if (t < s) {
      slo[t] = min(slo[t], slo[t + s]);
      shi[t] = max(shi[t], shi[t + s]);
    }
    __syncthreads();
  }
  if (t == 0) {
    int l = slo[0], h = shi[0];
    if (h < 0) { bnd[2 * ft] = 0; bnd[2 * ft + 1] = 0; }
    else {
      bnd[2 * ft] = l >> 5;
      bnd[2 * ft + 1] = min((h >> 5) + 1, nks);
    }
  }
}

// ---- standalone preps for the fallback path ----
__global__ void prep_A(const float* __restrict__ ww, int K, int nks,
                       bh8* __restrict__ Aarr) {
  int idx = blockIdx.x * 256 + threadIdx.x;
  if (idx < 7 * nks * 64) prepA_item(ww, K, nks, idx, Aarr);
}
__global__ void prep_bounds(const float* __restrict__ ww, int K, int nks,
                            int* __restrict__ bnd) {
  __shared__ int slo[256], shi[256];
  int ft = blockIdx.x, t = threadIdx.x;
  int lo = K, hi = -1;
  for (int m = t; m < 16 * K; m += 256) {
    int f = ft * 16 + m / K, k = m % K;
    if (ww[(size_t)f * K + k] != 0.f) { lo = min(lo, k); hi = max(hi, k); }
  }
  slo[t] = lo; shi[t] = hi;
  __syncthreads();
  for (int s = 128; s > 0; s >>= 1) {
    if (t < s) {
      slo[t] = min(slo[t], slo[t + s]);
      shi[t] = max(shi[t], shi[t + s]);
    }
    __syncthreads();
  }
  if (t == 0) {
    int l = slo[0], h = shi[0];
    if (h < 0) { bnd[2 * ft] = 0; bnd[2 * ft + 1] = 0; }
    else {
      bnd[2 * ft] = l >> 5;
      bnd[2 * ft + 1] = min((h >> 5) + 1, nks);
    }
  }
}

__device__ __forceinline__ void conv4acc(const float (&p)[4][4],
                                         const float (&w9)[9],
                                         float (&acc)[4]) {
  #pragma unroll
  for (int dy = 0; dy < 2; ++dy)
    #pragma unroll
    for (int dx = 0; dx < 2; ++dx) {
      float a = 0.f;
      #pragma unroll
      for (int dr = 0; dr < 3; ++dr)
        #pragma unroll
        for (int dc = 0; dc < 3; ++dc)
          a = fmaf(p[dy + dr][dx + dc], w9[dr * 3 + dc], a);
      acc[dy * 2 + dx] += a;
    }
}

__device__ __forceinline__ void load_patch(const unsigned short* su, int baseEl,
                                           int ldEl, float (&p)[4][4]) {
  #pragma unroll
  for (int i = 0; i < 4; ++i) {
    unsigned a = *(const unsigned*)(su + baseEl + i * ldEl);
    unsigned b = *(const unsigned*)(su + baseEl + i * ldEl + 2);
    p[i][0] = f_lo(a); p[i][1] = f_hi(a);
    p[i][2] = f_lo(b); p[i][3] = f_hi(b);
  }
}

// CWT phase body (PRE variant selectable); writes bf16 img into su.
template <bool PRE>
__device__ __forceinline__ void cwt_phase(unsigned short* su, int tid,
                                          const float* __restrict__ ww,
                                          const bh8* __restrict__ Aarr,
                                          const int* __restrict__ bnd,
                                          int K, int nks) {
  const int wid = __builtin_amdgcn_readfirstlane(tid >> 6);
  const int lane = tid & 63;
  const int koff = (lane >> 4) * 8;
  #pragma unroll 1
  for (int tile = wid; tile < 49; tile += NTH / 64) {
    const int ft = tile / 7, jt = tile - ft * 7;
    int klo = 0, khi = nks;
    if (PRE) { klo = bnd[2 * ft]; khi = bnd[2 * ft + 1]; }
    const int jcol = jt * 16 + (lane & 15);
    const int selj = (jcol == NF - 1)
        ? (XLEN - 1)
        : (int)((double)jcol * ((double)(XLEN - 1) / (double)(NF - 1)));
    fv4 acc = {0.f, 0.f, 0.f, 0.f};
    for (int ks = klo; ks < khi; ++ks) {
      const int kbase = selj + (ks << 5) + koff;
      const int par = kbase & 1;
      const int e0 = kbase - par;
      const unsigned* ph = (const unsigned*)(su + (par ? X1H : X0H) + e0);
      union { bh8 v; unsigned u[4]; } bh_;
      #pragma unroll
      for (int j = 0; j < 4; ++j) bh_.u[j] = ph[j];
      bh8 ah;
      if (PRE) {
        ah = Aarr[((size_t)ft * nks + ks) * 64 + lane];
      } else {
        const int frow = ft * 16 + (lane & 15);
        union { bh8 s; unsigned short h[8]; } ha;
        #pragma unroll
        for (int e = 0; e < 8; ++e) {
          int k = (ks << 5) + koff + e;
          float v = (k < K) ? ww[(size_t)frow * K + k] : 0.f;
          ha.h[e] = bfbits(v);
        }
        ah = ha.s;
      }
      acc = __builtin_amdgcn_mfma_f32_16x16x32_bf16(ah, bh_.v, acc, 0, 0, 0);
    }
    const int col = jt * 16 + (lane & 15) + 1;
    const int fbase = ft * 16 + (lane >> 4) * 4 + 1;
    #pragma unroll
    for (int r = 0; r < 4; ++r)
      su[IMG_OFF + (fbase + r) * IMG_LD + col] = bfbits(acc[r]);
  }
}

// ================= split kernel A: CWT + conv1 -> h1 (global) ==========
// h1g layout: PLANE-major u32: h1u[plane][3136], plane=0..2 (bf16 pairs).
__global__ __launch_bounds__(NTH, 4) void k_cwt_conv1(
    const float* __restrict__ x, const bh8* __restrict__ Aarr,
    const int* __restrict__ bnd, int K, int nks,
    const float* __restrict__ c1w, const float* __restrict__ c1b,
    unsigned* __restrict__ h1g) {
  extern __shared__ unsigned short su[];
  const int b = blockIdx.x;
  const int tid = threadIdx.x;
  const int pad = (K - 1) >> 1;

  for (int m = tid; m < 452; m += NTH) {  // img halo ring
    int r, c;
    if (m < 114) { r = 0; c = m; }
    else if (m < 228) { r = 113; c = m - 114; }
    else if (m < 340) { r = m - 228 + 1; c = 0; }
    else { r = m - 340 + 1; c = 113; }
    su[IMG_OFF + r * IMG_LD + c] = 0;
  }
  for (int i = tid; i < 1024; i += NTH) {
    float f0 = 0.f, f1 = 0.f;
    int xi = i - pad;
    if (xi >= 0 && xi < XLEN) f0 = x[(size_t)b * XLEN + xi];
    if (xi + 1 >= 0 && xi + 1 < XLEN) f1 = x[(size_t)b * XLEN + xi + 1];
    su[X0H + i] = bfbits(f0);
    su[X1H + i] = bfbits(f1);
  }
  __syncthreads();

  cwt_phase<true>(su, tid, nullptr, Aarr, bnd, K, nks);
  __syncthreads();

  // conv1 packed-f32 -> h1 plane-major (coalesced u32 stores)
  unsigned* h1s = h1g + (size_t)b * 9408;
  for (int it = tid; it < 3136; it += NTH) {
    int pr = it / 56, pc = it - pr * 56;
    float p[4][4];
    load_patch(su, IMG_OFF + (pr * 2) * IMG_LD + pc * 2, IMG_LD, p);
    f32x2 pq[4][3];
    #pragma unroll
    for (int r = 0; r < 4; ++r)
      #pragma unroll
      for (int c = 0; c < 3; ++c) pq[r][c] = f32x2{p[r][c], p[r][c + 1]};
    union { unsigned w[3]; unsigned short h[6]; } ou;
    #pragma unroll
    for (int oc = 0; oc < 6; ++oc) {
      f32x2 a0 = {c1b[oc], c1b[oc]};
      f32x2 a1 = a0;
      #pragma unroll
      for (int dr = 0; dr < 3; ++dr)
        #pragma unroll
        for (int dc = 0; dc < 3; ++dc) {
          float w = c1w[oc * 9 + dr * 3 + dc];
          f32x2 wv = {w, w};
          a0 = __builtin_elementwise_fma(pq[dr][dc], wv, a0);
          a1 = __builtin_elementwise_fma(pq[dr + 1][dc], wv, a1);
        }
      float m = fmaxf(fmaxf(a0.x, a0.y), fmaxf(a1.x, a1.y));
      ou.h[oc] = bfbits(fmaxf(m, 0.f));
    }
    h1s[it] = ou.w[0];
    h1s[3136 + it] = ou.w[1];
    h1s[6272 + it] = ou.w[2];
  }
}

// ================= split kernel B1: conv2 -> h2 (global) ===============
__global__ __launch_bounds__(NTH, 4) void k_conv2(
    const unsigned* __restrict__ h1g, const bh8* __restrict__ wcf,
    const float* __restrict__ c2b, unsigned* __restrict__ h2g) {
  extern __shared__ unsigned short su[];
  unsigned* su32 = (unsigned*)su;
  const int b = blockIdx.x;
  const int tid = threadIdx.x;
  const int lane = tid & 63, wid = tid >> 6;
  const int oc_a = lane & 15;
  const int row0 = (lane >> 4) * 4;

  for (int m = tid; m < 228; m += NTH) {  // halo ring
    int r, c;
    if (m < 58) { r = 0; c = m; }
    else if (m < 116) { r = 57; c = m - 58; }
    else if (m < 172) { r = m - 116 + 1; c = 0; }
    else { r = m - 172 + 1; c = 57; }
    ((uint4*)su)[r * 58 + c] = uint4{0, 0, 0, 0};
  }
  {  // stage h1 planes (coalesced reads) + zero word3
    const unsigned* g = h1g + (size_t)b * 9408;
    for (int i2 = tid; i2 < 9408; i2 += NTH) {
      int plane = i2 / 3136, pt = i2 - plane * 3136;
      int pr = pt / 56, pc = pt - pr * 56;
      su32[((pr + 1) * 58 + (pc + 1)) * 4 + plane] = g[i2];
    }
    for (int pt = tid; pt < 3136; pt += NTH) {
      int pr = pt / 56, pc = pt - pr * 56;
      su32[((pr + 1) * 58 + (pc + 1)) * 4 + 3] = 0;
    }
  }
  bh8 afr[3];
  #pragma unroll
  for (int m = 0; m < 3; ++m) afr[m] = wcf[m * 64 + lane];
  float biasv[4];
  #pragma unroll
  for (int r = 0; r < 4; ++r)
    biasv[r] = (row0 + r < 12) ? c2b[row0 + r] : 0.f;
  __syncthreads();

  unsigned* h2s = h2g + (size_t)b * 4704;
  for (int t = wid; t < 196; t += NTH / 64) {
    int n = t * 16 + oc_a;
    int p = n >> 2, q = n & 3;
    int pr = p / 28, pc = p - pr * 28;
    int r = pr * 2 + (q >> 1), c = pc * 2 + (q & 1);
    int base = (r * 58 + c) * 8;
    fv4 acc = {biasv[0], biasv[1], biasv[2], biasv[3]};
    #pragma unroll
    for (int m = 0; m < 3; ++m) {
      int tap = m * 4 + (lane >> 4);
      if (tap > 8) tap = 8;
      int dr = tap / 3, dc = tap - dr * 3;
      bh8 bv = *(const bh8*)(su + base + (dr * 58 + dc) * 8);
      acc = __builtin_amdgcn_mfma_f32_16x16x32_bf16(afr[m], bv, acc, 0, 0, 0);
    }
    union { uint2 v; unsigned short h[4]; } ou;
    #pragma unroll
    for (int r4 = 0; r4 < 4; ++r4) {
      float v = acc[r4];
      v = fmaxf(v, __shfl_xor(v, 1));
      v = fmaxf(v, __shfl_xor(v, 2));
      ou.h[r4] = bfbits(fmaxf(v, 0.f));
    }
    if ((lane & 3) == 0 && row0 < 12) {
      int w = row0 >> 1;  // 0,2,4
      h2s[w * 784 + p] = ou.v.x;
      h2s[(w + 1) * 784 + p] = ou.v.y;
    }
  }
}

// ============ split kernel B2: conv3+conv4 -> h4 (global bf16) =========
__global__ __launch_bounds__(NTH, 4) void k_tail(
    const unsigned* __restrict__ h2g, const bh8* __restrict__ wcf,
    const float* __restrict__ c3b, const float* __restrict__ c4b,
    unsigned short* __restrict__ h4g) {
  extern __shared__ unsigned short su[];
  unsigned* su32 = (unsigned*)su;
  const int b = blockIdx.x;
  const int tid = threadIdx.x;
  const int lane = tid & 63, wid = tid >> 6;
  const int oc_a = lane & 15;
  const int koff = (lane >> 4) * 8;
  const int row0 = (lane >> 4) * 4;
  const int icoff = koff & 15;
  const int taphalf = koff >> 4;

  for (int m = tid; m < 116; m += NTH) {  // h2 halo ring
    int r, c;
    if (m < 30) { r = 0; c = m; }
    else if (m < 60) { r = 29; c = m - 30; }
    else if (m < 88) { r = m - 60 + 1; c = 0; }
    else { r = m - 88 + 1; c = 29; }
    ((uint4*)su)[(r * 30 + c) * 2] = uint4{0, 0, 0, 0};
    ((uint4*)su)[(r * 30 + c) * 2 + 1] = uint4{0, 0, 0, 0};
  }
  for (int m = tid; m < 60; m += NTH) {  // h3 halo ring
    int r, c;
    if (m < 16) { r = 0; c = m; }
    else if (m < 32) { r = 15; c = m - 16; }
    else if (m < 46) { r = m - 32 + 1; c = 0; }
    else { r = m - 46 + 1; c = 15; }
    ((uint4*)(su + T_H3))[(r * 16 + c) * 2] = uint4{0, 0, 0, 0};
    ((uint4*)(su + T_H3))[(r * 16 + c) * 2 + 1] = uint4{0, 0, 0, 0};
  }
  {  // stage h2 planes (coalesced reads) + zero words 6,7
    const unsigned* g = h2g + (size_t)b * 4704;
    for (int i2 = tid; i2 < 4704; i2 += NTH) {
      int plane = i2 / 784, pt = i2 - plane * 784;
      int pr = pt / 28, pc = pt - pr * 28;
      su32[((pr + 1) * 30 + (pc + 1)) * 8 + plane] = g[i2];
    }
    for (int m = tid; m < 1568; m += NTH) {
      int pt = m >> 1, w = 6 + (m & 1);
      int pr = pt / 28, pc = pt - pr * 28;
      su32[((pr + 1) * 30 + (pc + 1)) * 8 + w] = 0;
    }
  }
  bh8 a3[5], a4[5];
  #pragma unroll
  for (int m = 0; m < 5; ++m) a3[m] = wcf[(3 + m) * 64 + lane];
  #pragma unroll
  for (int m = 0; m < 5; ++m) a4[m] = wcf[(8 + m) * 64 + lane];
  float bias3[4], bias4[4];
  #pragma unroll
  for (int r = 0; r < 4; ++r) {
    bias3[r] = (row0 + r < 12) ? c3b[row0 + r] : 0.f;
    bias4[r] = (row0 + r < 12) ? c4b[row0 + r] : 0.f;
  }
  __syncthreads();

  for (int t = wid; t < 49; t += NTH / 64) {
    int n = t * 16 + oc_a;
    int p = n >> 2, q = n & 3;
    int pr = p / 14, pc = p - pr * 14;
    int r = pr * 2 + (q >> 1), c = pc * 2 + (q & 1);
    int base = (r * 30 + c) * 16 + icoff;
    fv4 acc = {bias3[0], bias3[1], bias3[2], bias3[3]};
    #pragma unroll
    for (int m = 0; m < 5; ++m) {
      int tap = m * 2 + taphalf;
      if (tap > 8) tap = 8;
      int dr = tap / 3, dc = tap - dr * 3;
      bh8 bv = *(const bh8*)(su + base + (dr * 30 + dc) * 16);
      acc = __builtin_amdgcn_mfma_f32_16x16x32_bf16(a3[m], bv, acc, 0, 0, 0);
    }
    union { uint2 v; unsigned short h[4]; } ou;
    #pragma unroll
    for (int r4 = 0; r4 < 4; ++r4) {
      float v = acc[r4];
      v = fmaxf(v, __shfl_xor(v, 1));
      v = fmaxf(v, __shfl_xor(v, 2));
      ou.h[r4] = bfbits(fmaxf(v, 0.f));
    }
    if ((lane & 3) == 0)
      *(uint2*)(su + T_H3 + ((pr + 1) * 16 + (pc + 1)) * 16 + row0) = ou.v;
  }
  __syncthreads();

  unsigned short* h4s = h4g + (size_t)b * 608;
  for (int t = wid; t < 13; t += NTH / 64) {
    int n = t * 16 + oc_a;
    int p = n >> 2, q = n & 3;
    int pp = (p < 49) ? p : 0;
    int pr = pp / 7, pc = pp - pr * 7;
    int r = pr * 2 + (q >> 1), c = pc * 2 + (q & 1);
    int base = T_H3 + (r * 16 + c) * 16 + icoff;
    fv4 acc = {bias4[0], bias4[1], bias4[2], bias4[3]};
    #pragma unroll
    for (int m = 0; m < 5; ++m) {
      int tap = m * 2 + taphalf;
      if (tap > 8) tap = 8;
      int dr = tap / 3, dc = tap - dr * 3;
      bh8 bv = *(const bh8*)(su + base + (dr * 16 + dc) * 16);
      acc = __builtin_amdgcn_mfma_f32_16x16x32_bf16(a4[m], bv, acc, 0, 0, 0);
    }
    #pragma unroll
    for (int r4 = 0; r4 < 4; ++r4) {
      float v = acc[r4];
      v = fmaxf(v, __shfl_xor(v, 1));
      v = fmaxf(v, __shfl_xor(v, 2));
      v = fmaxf(v, 0.f);
      int oc = row0 + r4;
      if ((lane & 3) == 0 && p < 49 && oc < 12)
        h4s[oc * 49 + pr * 7 + pc] = bfbits(v);
    }
  }
}

// ============ k_fc: batched fc1 (MFMA) + fc2 + softmax ============
__global__ __launch_bounds__(64) void k_fc(
    const unsigned short* __restrict__ h4g, const bh8* __restrict__ w1f,
    const float* __restrict__ f1b, const float* __restrict__ f2w,
    const float* __restrict__ f2b, int nsamp, float* __restrict__ out) {
  __shared__ float fcs[16][49];
  const int lane = threadIdx.x;
  const int sbase = blockIdx.x * 16;
  const int scol = lane & 15;
  const int koff = (lane >> 4) * 8;
  const int row0 = (lane >> 4) * 4;
  int srow = sbase + scol;
  if (srow >= nsamp) srow = nsamp - 1;
  const unsigned short* hrow = h4g + (size_t)srow * 608 + koff;

  fv4 acc[3];
  #pragma unroll
  for (int ft = 0; ft < 3; ++ft) acc[ft] = fv4{0.f, 0.f, 0.f, 0.f};
  for (int ks = 0; ks < 19; ++ks) {
    bh8 bv = *(const bh8*)(hrow + ks * 32);
    #pragma unroll
    for (int ft = 0; ft < 3; ++ft) {
      bh8 av = w1f[(ft * 19 + ks) * 64 + lane];
      acc[ft] = __builtin_amdgcn_mfma_f32_16x16x32_bf16(av, bv, acc[ft],
                                                        0, 0, 0);
    }
  }
  #pragma unroll
  for (int ft = 0; ft < 3; ++ft)
    #pragma unroll
    for (int r = 0; r < 4; ++r) {
      int oc = ft * 16 + row0 + r;
      fcs[scol][oc] = fmaxf(acc[ft][r] + f1b[oc], 0.f);
    }
  __syncthreads();
  if (lane < 16 && sbase + lane < nsamp) {
    float l[4];
    #pragma unroll
    for (int o = 0; o < 4; ++o) {
      float s = f2b[o];
      for (int i = 0; i < 48; ++i) s += fcs[lane][i] * f2w[o * 48 + i];
      l[o] = s;
    }
    float m = fmaxf(fmaxf(l[0], l[1]), fmaxf(l[2], l[3]));
    float e0 = expf(l[0] - m), e1 = expf(l[1] - m);
    float e2 = expf(l[2] - m), e3 = expf(l[3] - m);
    float ss = e0 + e1 + e2 + e3;
    float* o4 = out + (size_t)(sbase + lane) * 4;
    o4[0] = e0 / ss; o4[1] = e1 / ss; o4[2] = e2 / ss; o4[3] = e3 / ss;
  }
}

// ================= fused fallback (register-table conv) ================
template <int NKS, int KREAL, int NOC, int OMODE>
__device__ __forceinline__ void conv_mfma(
    unsigned short* su, float* sfl, unsigned short* gout, int tid,
    int inOff, int inLD, int inCh,
    int outOff, int outLD, int outCh, int plW,
    int NT, int NPOOL,
    const float* __restrict__ wgt, const float* __restrict__ bias) {
  const int lane = tid & 63;
  const int wid = tid >> 6;
  const int oc_a = lane & 15;
  const int koff = (lane >> 4) * 8;
  const int row0 = (lane >> 4) * 4;

  bh8 afr[NKS];
  unsigned opk[NKS][4];
  #pragma unroll
  for (int ks = 0; ks < NKS; ++ks) {
    union { bh8 s; unsigned short h[8]; } au;
    #pragma unroll
    for (int e = 0; e < 8; ++e) {
      int k = ks * 32 + koff + e;
      au.h[e] = (oc_a < NOC && k < KREAL)
                    ? bfbits(wgt[oc_a * KREAL + k]) : (unsigned short)0;
    }
    afr[ks] = au.s;
    #pragma unroll
    for (int e2 = 0; e2 < 4; ++e2) {
      unsigned o01[2];
      #pragma unroll
      for (int h = 0; h < 2; ++h) {
        int k = ks * 32 + koff + 2 * e2 + h;
        int kc = (k < KREAL) ? k : 0;
        int ic = kc / 9, rem = kc - ic * 9;
        o01[h] = (unsigned)(ic * inCh + (rem / 3) * inLD +
                            (rem - (rem / 3) * 3));
      }
      opk[ks][e2] = o01[0] | (o01[1] << 16);
    }
  }
  float biasv[4];
  #pragma unroll
  for (int r = 0; r < 4; ++r)
    biasv[r] = (row0 + r < NOC) ? bias[row0 + r] : 0.f;

  for (int t = wid; t < NT; t += NTH / 64) {
    int n = t * 16 + oc_a;
    int p = n >> 2, q = n & 3;
    int pp = (p < NPOOL) ? p : 0;
    int pr = pp / plW, pc = pp - pr * plW;
    int r = pr * 2 + (q >> 1), c = pc * 2 + (q & 1);
    int base = inOff + r * inLD + c;
    fv4 acc = {biasv[0], biasv[1], biasv[2], biasv[3]};
    #pragma unroll
    for (int ks = 0; ks < NKS; ++ks) {
      union { bh8 v; unsigned short h[8]; } bu;
      #pragma unroll
      for (int e2 = 0; e2 < 4; ++e2) {
        unsigned pk = opk[ks][e2];
        bu.h[2 * e2] = su[base + (pk & 0xffffu)];
        bu.h[2 * e2 + 1] = su[base + (pk >> 16)];
      }
      acc = __builtin_amdgcn_mfma_f32_16x16x32_bf16(afr[ks], bu.v, acc, 0, 0, 0);
    }
    #pragma unroll
    for (int r4 = 0; r4 < 4; ++r4) {
      float v = acc[r4];
      v = fmaxf(v, __shfl_xor(v, 1));
      v = fmaxf(v, __shfl_xor(v, 2));
      v = fmaxf(v, 0.f);
      int oc = row0 + r4;
      if ((lane & 3) == 0 && oc < NOC && p < NPOOL) {
        if (OMODE == 1)
          sfl[outOff + oc * (plW * plW) + pr * plW + pc] = v;
        else if (OMODE == 2)
          gout[oc * NPOOL + pr * plW + pc] = bfbits(v);
        else
          su[outOff + oc * outCh + (pr + 1) * outLD + (pc + 1)] = bfbits(v);
      }
    }
  }
}

template <bool PRE>
__global__ __launch_bounds__(NTH, 4) void fused_convnet(
    const float* __restrict__ x, const float* __restrict__ ww,
    const bh8* __restrict__ Aarr, const int* __restrict__ bnd,
    int K, int nks,
    const float* __restrict__ c1w, const float* __restrict__ c1b,
    const float* __restrict__ c2w, const float* __restrict__ c2b,
    const float* __restrict__ c3w, const float* __restrict__ c3b,
    const float* __restrict__ c4w, const float* __restrict__ c4b,
    const float* __restrict__ f1w, const float* __restrict__ f1b,
    const float* __restrict__ f2w, const float* __restrict__ f2b,
    float* __restrict__ out) {
  extern __shared__ unsigned short su[];
  float* sfl = (float*)su;
  const int b = blockIdx.x;
  const int tid = threadIdx.x;
  const int pad = (K - 1) >> 1;

  for (int m = tid; m < 452; m += NTH) {
    int r, c;
    if (m < 114) { r = 0; c = m; }
    else if (m < 228) { r = 113; c = m - 114; }
    else if (m < 340) { r = m - 228 + 1; c = 0; }
    else { r = m - 340 + 1; c = 113; }
    su[IMG_OFF + r * IMG_LD + c] = 0;
  }
  for (int m = tid; m < 1368; m += NTH) {
    int ch = m / 228, w = m - ch * 228, r, c;
    if (w < 58) { r = 0; c = w; }
    else if (w < 116) { r = 57; c = w - 58; }
    else if (w < 172) { r = w - 116 + 1; c = 0; }
    else { r = w - 172 + 1; c = 57; }
    su[H1_OFF + ch * 3364 + r * 58 + c] = 0;
  }
  for (int i = tid; i < 1024; i += NTH) {
    float f0 = 0.f, f1 = 0.f;
    int xi = i - pad;
    if (xi >= 0 && xi < XLEN) f0 = x[(size_t)b * XLEN + xi];
    if (xi + 1 >= 0 && xi + 1 < XLEN) f1 = x[(size_t)b * XLEN + xi + 1];
    su[X0H + i] = bfbits(f0);
    su[X1H + i] = bfbits(f1);
  }
  __syncthreads();

  cwt_phase<PRE>(su, tid, ww, Aarr, bnd, K, nks);
  __syncthreads();

  for (int it = tid; it < 3136; it += NTH) {
    int pr = it / 56, pc = it - pr * 56;
    float p[4][4];
    load_patch(su, IMG_OFF + (pr * 2) * IMG_LD + pc * 2, IMG_LD, p);
    #pragma unroll
    for (int oc = 0; oc < 6; ++oc) {
      float w9[9];
      #pragma unroll
      for (int t = 0; t < 9; ++t) w9[t] = c1w[oc * 9 + t];
      float acc[4] = {c1b[oc], c1b[oc], c1b[oc], c1b[oc]};
      conv4acc(p, w9, acc);
      float m = fmaxf(fmaxf(acc[0], acc[1]), fmaxf(acc[2], acc[3]));
      su[H1_OFF + oc * 3364 + (pr + 1) * 58 + (pc + 1)] = bfbits(fmaxf(m, 0.f));
    }
  }
  __syncthreads();

  for (int m = tid; m < 1392; m += NTH) {
    int ch = m / 116, w = m - ch * 116, r, c;
    if (w < 30) { r = 0; c = w; }
    else if (w < 60) { r = 29; c = w - 30; }
    else if (w < 88) { r = w - 60 + 1; c = 0; }
    else { r = w - 88 + 1; c = 29; }
    su[H2_OFF + ch * 900 + r * 30 + c] = 0;
  }
  for (int m = tid; m < 720; m += NTH) {
    int ch = m / 60, w = m - ch * 60, r, c;
    if (w < 16) { r = 0; c = w; }
    else if (w < 32) { r = 15; c = w - 16; }
    else if (w < 46) { r = w - 32 + 1; c = 0; }
    else { r = w - 46 + 1; c = 15; }
    su[H3_OFF + ch * 256 + r * 16 + c] = 0;
  }
  __syncthreads();

  conv_mfma<2, 54, 12, 0>(su, sfl, nullptr, tid, H1_OFF, 58, 3364,
                          H2_OFF, 30, 900, 28, 196, 784, c2w, c2b);
  __syncthreads();

  conv_mfma<4, 108, 12, 0>(su, sfl, nullptr, tid, H2_OFF, 30, 900,
                           H3_OFF, 16, 256, 14, 49, 196, c3w, c3b);
  __syncthreads();

  conv_mfma<4, 108, 12, 1>(su, sfl, nullptr, tid, H3_OFF, 16, 256,
                           H4_F, 0, 0, 7, 13, 49, c4w, c4b);
  __syncthreads();

  {
    int wv = tid >> 6, ln = tid & 63;
    for (int o = wv; o < 48; o += NTH / 64) {
      float s = 0.f;
      for (int i = ln; i < 588; i += 64)
        s += sfl[H4_F + i] * f1w[(size_t)o * 588 + i];
      #pragma unroll
      for (int off = 32; off > 0; off >>= 1) s += __shfl_down(s, off);
      if (ln == 0) sfl[FC1_F + o] = fmaxf(s + f1b[o], 0.f);
    }
  }
  __syncthreads();
  if (tid < 4) {
    float s = f2b[tid];
    for (int i = 0; i < 48; ++i) s += sfl[FC1_F + i] * f2w[tid * 48 + i];
    sfl[LG_F + tid] = s;
  }
  __syncthreads();
  if (tid < 4) {
    float l0 = sfl[LG_F + 0], l1 = sfl[LG_F + 1];
    float l2 = sfl[LG_F + 2], l3 = sfl[LG_F + 3];
    float m = fmaxf(fmaxf(l0, l1), fmaxf(l2, l3));
    float e0 = expf(l0 - m), e1 = expf(l1 - m);
    float e2 = expf(l2 - m), e3 = expf(l3 - m);
    float ssum = e0 + e1 + e2 + e3;
    out[(size_t)b * 4 + tid] = expf(sfl[LG_F + tid] - m) / ssum;
  }
}

extern "C" void kernel_launch(void* const* d_in, const int* in_sizes, int n_in,
                              void* d_out, int out_size, void* d_ws,
                              size_t ws_size, hipStream_t stream) {
  const float* x   = (const float*)d_in[0];
  const float* ww  = (const float*)d_in[1];
  const float* c1w = (const float*)d_in[2];
  const float* c1b = (const float*)d_in[3];
  const float* c2w = (const float*)d_in[4];
  const float* c2b = (const float*)d_in[5];
  const float* c3w = (const float*)d_in[6];
  const float* c3b = (const float*)d_in[7];
  const float* c4w = (const float*)d_in[8];
  const float* c4b = (const float*)d_in[9];
  const float* f1w = (const float*)d_in[10];
  const float* f1b = (const float*)d_in[11];
  const float* f2w = (const float*)d_in[12];
  const float* f2b = (const float*)d_in[13];
  float* out = (float*)d_out;

  const int B = in_sizes[0] / XLEN;
  const int K = in_sizes[1] / NF;  // 561
  const int nks = (K + 31) / 32;   // 18

  const int items = 7 * nks * 64;
  const size_t aoff = (size_t)items * sizeof(bh8);   // 129024 B
  const size_t abytes = aoff + 64;                   // + bnd
  const size_t w1off = abytes;
  const size_t w1bytes = (size_t)3648 * sizeof(bh8); // 58368 B
  const size_t wcoff = w1off + w1bytes;
  const size_t wcbytes = (size_t)832 * sizeof(bh8);  // 13312 B
  const size_t h1off = wcoff + wcbytes;
  const size_t h1bytes = (size_t)B * 18816 * 2;
  const size_t h2off = h1off + h1bytes;
  const size_t h2bytes = (size_t)B * 9408 * 2;
  const size_t h4off = h2off + h2bytes;
  const size_t h4bytes = (size_t)B * 608 * 2;
  const size_t need3 = h4off + h4bytes;

  bh8* Aarr = (bh8*)d_ws;
  int* bnd = (int*)((char*)d_ws + aoff);
  bh8* w1f = (bh8*)((char*)d_ws + w1off);
  bh8* wcf = (bh8*)((char*)d_ws + wcoff);
  unsigned* h1g = (unsigned*)((char*)d_ws + h1off);
  unsigned* h2g = (unsigned*)((char*)d_ws + h2off);
  unsigned short* h4g = (unsigned short*)((char*)d_ws + h4off);

  if (ws_size >= need3) {
    const int nmap = items + 3648 + 832;
    const int nblk = (nmap + 255) / 256;
    hipLaunchKernelGGL(prep_all, dim3(nblk + 7), dim3(256), 0, stream,
                       ww, K, nks, f1w, c2w, c3w, c4w, items, nblk,
                       Aarr, w1f, wcf, bnd);
    hipFuncSetAttribute((const void*)k_cwt_conv1,
                        hipFuncAttributeMaxDynamicSharedMemorySize,
                        KA_TOT * 2);
    hipFuncSetAttribute((const void*)k_conv2,
                        hipFuncAttributeMaxDynamicSharedMemorySize,
                        KB1_TOT * 2);
    hipFuncSetAttribute((const void*)k_tail,
                        hipFuncAttributeMaxDynamicSharedMemorySize,
                        KB2_TOT * 2);
    hipLaunchKernelGGL(k_cwt_conv1, dim3(B), dim3(NTH), KA_TOT * 2, stream,
                       x, Aarr, bnd, K, nks, c1w, c1b, h1g);
    hipLaunchKernelGGL(k_conv2, dim3(B), dim3(NTH), KB1_TOT * 2, stream,
                       h1g, wcf, c2b, h2g);
    hipLaunchKernelGGL(k_tail, dim3(B), dim3(NTH), KB2_TOT * 2, stream,
                       h2g, wcf, c3b, c4b, h4g);
    hipLaunchKernelGGL(k_fc, dim3((B + 15) / 16), dim3(64), 0, stream,
                       h4g, w1f, f1b, f2w, f2b, B, out);
  } else if (ws_size >= abytes) {
    hipLaunchKernelGGL(prep_A, dim3((items + 255) / 256), dim3(256), 0, stream,
                       ww, K, nks, Aarr);
    hipLaunchKernelGGL(prep_bounds, dim3(7), dim3(256), 0, stream,
                       ww, K, nks, bnd);
    hipFuncSetAttribute((const void*)fused_convnet<true>,
                        hipFuncAttributeMaxDynamicSharedMemorySize,
                        TOT_E * 2);
    hipLaunchKernelGGL(fused_convnet<true>, dim3(B), dim3(NTH), TOT_E * 2,
                       stream, x, ww, Aarr, bnd, K, nks, c1w, c1b, c2w, c2b,
                       c3w, c3b, c4w, c4b, f1w, f1b, f2w, f2b, out);
  } else {
    hipFuncSetAttribute((const void*)fused_convnet<false>,
                        hipFuncAttributeMaxDynamicSharedMemorySize,
                        TOT_E * 2);
    hipLaunchKernelGGL(fused_convnet<false>, dim3(B), dim3(NTH), TOT_E * 2,
                       stream, x, ww, Aarr, bnd, K, nks, c1w, c1b, c2w, c2b,
                       c3w, c3b, c4w, c4b, f1w, f1b, f2w, f2b, out);
  }
}